// Round 6
// baseline (2990.672 us; speedup 1.0000x reference)
//
#include <hip/hip_runtime.h>
#include <float.h>

#define B_ 16
#define N_ 2048
#define KNN 20

typedef unsigned short u16;
typedef __attribute__((ext_vector_type(8))) short bf16x8;
typedef __attribute__((ext_vector_type(4))) float f32x4;

__device__ inline u16 bfhi(float v) {
    union { float f; unsigned u; } x; x.f = v;
    unsigned r = x.u + 0x7FFFu + ((x.u >> 16) & 1u);
    return (u16)(r >> 16);
}
__device__ inline u16 bflo(float v, u16 h) {
    union { unsigned u; float f; } y; y.u = ((unsigned)h) << 16;
    return bfhi(v - y.f);
}
__device__ inline unsigned fkey(float v) {
    union { float f; unsigned u; } x;
    x.f = fmaxf(v, 0.f);
    return x.u & 0x7FFFFFFFu;
}
__device__ inline unsigned umin_(unsigned a, unsigned b) { return a < b ? a : b; }

// ---------------- bitonic sort across 64 lanes (ascending by key) ----------------
template <bool P>
__device__ inline void bitonic64(unsigned& key, unsigned& pay, int lane) {
#pragma unroll
    for (int k = 2; k <= 64; k <<= 1) {
#pragma unroll
        for (int j = k >> 1; j > 0; j >>= 1) {
            unsigned ok = __shfl_xor(key, j);
            unsigned op = P ? __shfl_xor(pay, j) : 0u;
            bool up = ((lane & k) == 0);
            bool lower = ((lane & j) == 0);
            bool takeOther = (up == lower) ? (ok < key) : (ok > key);
            if (takeOther) { key = ok; if (P) pay = op; }
        }
    }
}

// ---------------- exact top-20 of 2048 (32 keys/lane) -> writes idx ----------------
__device__ inline void select20(const unsigned* kr, int lane,
                                unsigned* klist, unsigned* ilist,
                                int* __restrict__ outIdx) {
    unsigned lm = kr[0];
#pragma unroll
    for (int i = 1; i < 32; ++i) lm = umin_(lm, kr[i]);
    unsigned dummy = 0, sk = lm;
    bitonic64<false>(sk, dummy, lane);
    unsigned S = __shfl(sk, 19);
    unsigned c = 0;
#pragma unroll
    for (int i = 0; i < 32; ++i) c += (kr[i] <= S) ? 1u : 0u;
    unsigned incl = c;
#pragma unroll
    for (int d = 1; d < 64; d <<= 1) {
        unsigned t = __shfl_up(incl, d);
        if (lane >= d) incl += t;
    }
    unsigned stot = __shfl(incl, 63);
    unsigned pos = incl - c;
    klist[lane] = 0xFFFFFFFFu;
    __syncthreads();
#pragma unroll
    for (int i = 0; i < 32; ++i) {
        if (kr[i] <= S) {
            if (pos < 64u) {
                klist[pos] = kr[i];
                ilist[pos] = ((unsigned)(i >> 2) << 8) + (unsigned)lane * 4u + (unsigned)(i & 3);
            }
            ++pos;
        }
    }
    __syncthreads();
    if (stot <= 64u) {
        unsigned key = klist[lane], pay = ilist[lane];
        bitonic64<true>(key, pay, lane);
        if (lane < KNN) outIdx[lane] = (int)pay;
    } else {
        unsigned taken = 0;
        for (int it = 0; it < KNN; ++it) {
            unsigned bk = 0xFFFFFFFFu; int bi = 0;
#pragma unroll
            for (int i = 0; i < 32; ++i) {
                bool better = (((taken >> i) & 1u) == 0u) && (kr[i] < bk);
                if (better) { bk = kr[i]; bi = i; }
            }
            unsigned bl = (unsigned)lane;
#pragma unroll
            for (int off = 32; off > 0; off >>= 1) {
                unsigned ok = __shfl_down(bk, off);
                unsigned ol = __shfl_down(bl, off);
                int oi = __shfl_down(bi, off);
                if (ok < bk) { bk = ok; bl = ol; bi = oi; }
            }
            bl = __shfl(bl, 0); bi = __shfl(bi, 0);
            if (lane == (int)bl) taken |= (1u << bi);
            if (lane == 0) outIdx[it] = (int)(((unsigned)(bi >> 2) << 8) + bl * 4u + (unsigned)(bi & 3));
        }
    }
}

// ---------------- exact top-20 of 512 (8 keys/lane) -> sorted regs in lanes 0..19 ----
__device__ inline void select20_512(const unsigned* kr, const unsigned* pay, int lane,
                                    unsigned* klist, unsigned* ilist,
                                    unsigned& okey, unsigned& opay) {
    unsigned lm = kr[0];
#pragma unroll
    for (int i = 1; i < 8; ++i) lm = umin_(lm, kr[i]);
    unsigned dummy = 0, sk = lm;
    bitonic64<false>(sk, dummy, lane);
    unsigned S = __shfl(sk, 19);
    unsigned c = 0;
#pragma unroll
    for (int i = 0; i < 8; ++i) c += (kr[i] <= S) ? 1u : 0u;
    unsigned incl = c;
#pragma unroll
    for (int d = 1; d < 64; d <<= 1) {
        unsigned t = __shfl_up(incl, d);
        if (lane >= d) incl += t;
    }
    unsigned stot = __shfl(incl, 63);
    unsigned pos = incl - c;
    klist[lane] = 0xFFFFFFFFu;
    __syncthreads();
#pragma unroll
    for (int i = 0; i < 8; ++i) {
        if (kr[i] <= S) {
            if (pos < 64u) { klist[pos] = kr[i]; ilist[pos] = pay[i]; }
            ++pos;
        }
    }
    __syncthreads();
    if (stot <= 64u) {
        okey = klist[lane]; opay = ilist[lane];
        bitonic64<true>(okey, opay, lane);
    } else {
        unsigned taken = 0;
        okey = 0xFFFFFFFFu; opay = 0u;
        for (int it = 0; it < KNN; ++it) {
            unsigned bk = 0xFFFFFFFFu, bp = 0u; int bi = 0;
#pragma unroll
            for (int i = 0; i < 8; ++i) {
                bool better = (((taken >> i) & 1u) == 0u) && (kr[i] < bk);
                if (better) { bk = kr[i]; bp = pay[i]; bi = i; }
            }
            unsigned bl = (unsigned)lane;
#pragma unroll
            for (int off = 32; off > 0; off >>= 1) {
                unsigned ok = __shfl_down(bk, off);
                unsigned op = __shfl_down(bp, off);
                unsigned ol = __shfl_down(bl, off);
                int oi = __shfl_down(bi, off);
                if (ok < bk) { bk = ok; bp = op; bl = ol; bi = oi; }
            }
            bk = __shfl(bk, 0); bp = __shfl(bp, 0); bl = __shfl(bl, 0); bi = __shfl(bi, 0);
            if (lane == (int)bl) taken |= (1u << bi);
            if (lane == it) { okey = bk; opay = bp; }
        }
    }
}

// ---------------- sq-norms from split cat ----------------
__global__ void sqnorm_split_kernel(const u16* __restrict__ hi, const u16* __restrict__ lo,
                                    int coloff, int C, float* __restrict__ sqn) {
    int t = blockIdx.x * 256 + threadIdx.x;
    if (t >= B_ * N_) return;
    const u16* rh = hi + (size_t)t * 512 + coloff;
    const u16* rl = lo + (size_t)t * 512 + coloff;
    float s = 0.f;
    for (int c = 0; c < C; ++c) {
        union { unsigned u; float f; } a, b;
        a.u = ((unsigned)rh[c]) << 16;
        b.u = ((unsigned)rl[c]) << 16;
        float v = a.f + b.f;
        s = fmaf(v, v, s);
    }
    sqn[t] = s;
}

// ---------------- fused knn for convs 2-4: MFMA dist tiles in LDS + inline top-20 ----
// grid (64, 16): 32 query rows per block, batch = blockIdx.y.
template <int C>
__launch_bounds__(256, 1)
__global__ void knn_fused_kernel(const u16* __restrict__ cathi, const u16* __restrict__ catlo,
                                 int coloff, const float* __restrict__ sqn,
                                 int* __restrict__ idx_out) {
    __shared__ u16 Ah[32][C + 8], Al[32][C + 8];
    __shared__ u16 Bh[128][C + 8], Bl[128][C + 8];
    __shared__ float dq[32][516];
    __shared__ unsigned kl[4][64], il[4][64];
    __shared__ float ssi[32];
    int tid = threadIdx.x, w = tid >> 6, lane = tid & 63;
    int b = blockIdx.y, r0 = blockIdx.x * 32;
    int l15 = lane & 15, l4 = lane >> 4;
    const int CV = C / 8;

    for (int v = tid; v < 32 * CV; v += 256) {
        int row = v / CV, kc = (v % CV) * 8;
        size_t src = (size_t)(b * N_ + r0 + row) * 512 + coloff + kc;
        *(uint4*)&Ah[row][kc] = *(const uint4*)&cathi[src];
        *(uint4*)&Al[row][kc] = *(const uint4*)&catlo[src];
    }
    if (tid < 32) ssi[tid] = sqn[b * N_ + r0 + tid];

    unsigned runk[8], runi[8];
#pragma unroll
    for (int rr = 0; rr < 8; ++rr) { runk[rr] = 0xFFFFFFFFu; runi[rr] = 0u; }

    for (int q = 0; q < 4; ++q) {
        for (int t = 0; t < 4; ++t) {
            int j0 = q * 512 + t * 128;
            __syncthreads();
            for (int v = tid; v < 128 * CV; v += 256) {
                int row = v / CV, kc = (v % CV) * 8;
                size_t src = (size_t)(b * N_ + j0 + row) * 512 + coloff + kc;
                *(uint4*)&Bh[row][kc] = *(const uint4*)&cathi[src];
                *(uint4*)&Bl[row][kc] = *(const uint4*)&catlo[src];
            }
            __syncthreads();
            f32x4 acc[2][2];
#pragma unroll
            for (int i = 0; i < 2; ++i)
#pragma unroll
                for (int j = 0; j < 2; ++j) acc[i][j] = (f32x4){0.f, 0.f, 0.f, 0.f};
#pragma unroll
            for (int ks = 0; ks < C / 32; ++ks) {
                int ko = ks * 32 + l4 * 8;
                bf16x8 a0h = *(const bf16x8*)&Ah[l15][ko];
                bf16x8 a1h = *(const bf16x8*)&Ah[16 + l15][ko];
                bf16x8 a0l = *(const bf16x8*)&Al[l15][ko];
                bf16x8 a1l = *(const bf16x8*)&Al[16 + l15][ko];
                bf16x8 b0h = *(const bf16x8*)&Bh[w * 32 + l15][ko];
                bf16x8 b1h = *(const bf16x8*)&Bh[w * 32 + 16 + l15][ko];
                bf16x8 b0l = *(const bf16x8*)&Bl[w * 32 + l15][ko];
                bf16x8 b1l = *(const bf16x8*)&Bl[w * 32 + 16 + l15][ko];
                acc[0][0] = __builtin_amdgcn_mfma_f32_16x16x32_bf16(a0h, b0h, acc[0][0], 0, 0, 0);
                acc[0][0] = __builtin_amdgcn_mfma_f32_16x16x32_bf16(a0h, b0l, acc[0][0], 0, 0, 0);
                acc[0][0] = __builtin_amdgcn_mfma_f32_16x16x32_bf16(a0l, b0h, acc[0][0], 0, 0, 0);
                acc[0][1] = __builtin_amdgcn_mfma_f32_16x16x32_bf16(a0h, b1h, acc[0][1], 0, 0, 0);
                acc[0][1] = __builtin_amdgcn_mfma_f32_16x16x32_bf16(a0h, b1l, acc[0][1], 0, 0, 0);
                acc[0][1] = __builtin_amdgcn_mfma_f32_16x16x32_bf16(a0l, b1h, acc[0][1], 0, 0, 0);
                acc[1][0] = __builtin_amdgcn_mfma_f32_16x16x32_bf16(a1h, b0h, acc[1][0], 0, 0, 0);
                acc[1][0] = __builtin_amdgcn_mfma_f32_16x16x32_bf16(a1h, b0l, acc[1][0], 0, 0, 0);
                acc[1][0] = __builtin_amdgcn_mfma_f32_16x16x32_bf16(a1l, b0h, acc[1][0], 0, 0, 0);
                acc[1][1] = __builtin_amdgcn_mfma_f32_16x16x32_bf16(a1h, b1h, acc[1][1], 0, 0, 0);
                acc[1][1] = __builtin_amdgcn_mfma_f32_16x16x32_bf16(a1h, b1l, acc[1][1], 0, 0, 0);
                acc[1][1] = __builtin_amdgcn_mfma_f32_16x16x32_bf16(a1l, b1h, acc[1][1], 0, 0, 0);
            }
#pragma unroll
            for (int i = 0; i < 2; ++i)
#pragma unroll
                for (int j = 0; j < 2; ++j) {
                    int qc = t * 128 + w * 32 + j * 16 + l15;
                    float sj = sqn[b * N_ + q * 512 + qc];
#pragma unroll
                    for (int r = 0; r < 4; ++r) {
                        int row = i * 16 + l4 * 4 + r;
                        dq[row][qc] = ssi[row] + sj - 2.f * acc[i][j][r];
                    }
                }
        }
        __syncthreads();
#pragma unroll
        for (int rr = 0; rr < 8; ++rr) {
            int row = w * 8 + rr;
            unsigned kr[8], pay[8];
#pragma unroll
            for (int h = 0; h < 2; ++h) {
                float4 v4 = *(const float4*)&dq[row][h * 256 + lane * 4];
                unsigned cb = (unsigned)(q * 512 + h * 256 + lane * 4);
                kr[h * 4 + 0] = fkey(v4.x); pay[h * 4 + 0] = cb;
                kr[h * 4 + 1] = fkey(v4.y); pay[h * 4 + 1] = cb + 1;
                kr[h * 4 + 2] = fkey(v4.z); pay[h * 4 + 2] = cb + 2;
                kr[h * 4 + 3] = fkey(v4.w); pay[h * 4 + 3] = cb + 3;
            }
            unsigned okey, opay;
            select20_512(kr, pay, lane, kl[w], il[w], okey, opay);
            unsigned mk = 0xFFFFFFFFu, mp = 0u;
            if (lane < 20) { mk = okey; mp = opay; }
            int srcl = (lane >= 20 && lane < 40) ? (lane - 20) : 0;
            unsigned tk = __shfl(runk[rr], srcl);
            unsigned tp = __shfl(runi[rr], srcl);
            if (lane >= 20 && lane < 40) { mk = tk; mp = tp; }
            bitonic64<true>(mk, mp, lane);
            if (lane < 20) { runk[rr] = mk; runi[rr] = mp; }
        }
    }
#pragma unroll
    for (int rr = 0; rr < 8; ++rr) {
        if (lane < 20)
            idx_out[((size_t)(b * N_) + r0 + w * 8 + rr) * KNN + lane] = (int)runi[rr];
    }
}

// select for conv1: distances straight from 3-D coords
__launch_bounds__(256)
__global__ void select3_kernel(const float* __restrict__ x, int* __restrict__ idx_out) {
    __shared__ __align__(16) float cx[N_], cy[N_], cz[N_];
    __shared__ unsigned kl[4][64], il[4][64];
    int tid = threadIdx.x, blk = blockIdx.x;
    int b = blk >> 9, n0 = (blk & 511) * 4;
    for (int i = tid; i < N_; i += 256) {
        const float* p = x + (size_t)(b * N_ + i) * 3;
        cx[i] = p[0]; cy[i] = p[1]; cz[i] = p[2];
    }
    __syncthreads();
    int w = tid >> 6, lane = tid & 63;
    int q = n0 + w;
    float qx = cx[q], qy = cy[q], qz = cz[q];
    unsigned kr[32];
#pragma unroll
    for (int j = 0; j < 8; ++j) {
        float4 vx = *(const float4*)&cx[j * 256 + lane * 4];
        float4 vy = *(const float4*)&cy[j * 256 + lane * 4];
        float4 vz = *(const float4*)&cz[j * 256 + lane * 4];
        float dx, dy, dz;
        dx = qx - vx.x; dy = qy - vy.x; dz = qz - vz.x;
        kr[j * 4 + 0] = fkey(fmaf(dx, dx, fmaf(dy, dy, dz * dz)));
        dx = qx - vx.y; dy = qy - vy.y; dz = qz - vz.y;
        kr[j * 4 + 1] = fkey(fmaf(dx, dx, fmaf(dy, dy, dz * dz)));
        dx = qx - vx.z; dy = qy - vy.z; dz = qz - vz.z;
        kr[j * 4 + 2] = fkey(fmaf(dx, dx, fmaf(dy, dy, dz * dz)));
        dx = qx - vx.w; dy = qy - vy.w; dz = qz - vz.w;
        kr[j * 4 + 3] = fkey(fmaf(dx, dx, fmaf(dy, dy, dz * dz)));
    }
    select20(kr, lane, kl[w], il[w], idx_out + ((size_t)(b * N_ + q)) * KNN);
}

// ---------------- weight prep ----------------
__global__ void wt_kernel(const float* __restrict__ w, const float* __restrict__ b,
                          float* __restrict__ wt, float* __restrict__ bt,
                          int C, int Cout) {
    int N2 = 2 * Cout;
    int t = blockIdx.x * 256 + threadIdx.x;
    if (t < C * N2) {
        int c = t / N2, d = t % N2;
        float v;
        if (d < Cout) v = w[c * Cout + d];
        else          v = w[(C + c) * Cout + (d - Cout)] - w[c * Cout + (d - Cout)];
        wt[t] = v;
    }
    if (t < N2) bt[t] = (t < Cout) ? 0.f : b[t - Cout];
}

__global__ void prep_edge_B(const float* __restrict__ w, const float* __restrict__ b,
                            u16* __restrict__ Bth, u16* __restrict__ Btl,
                            float* __restrict__ bt, int C, int Cout) {
    int N2 = 2 * Cout;
    int t = blockIdx.x * 256 + threadIdx.x;
    if (t < N2 * C) {
        int d = t / C, c = t % C;
        float v = (d < Cout) ? w[c * Cout + d]
                             : (w[(C + c) * Cout + (d - Cout)] - w[c * Cout + (d - Cout)]);
        u16 h = bfhi(v);
        Bth[t] = h; Btl[t] = bflo(v, h);
    }
    if (t < N2) bt[t] = (t < Cout) ? 0.f : b[t - Cout];
}

__global__ void prep_w5_kernel(const float* __restrict__ w5,
                               u16* __restrict__ Bth, u16* __restrict__ Btl) {
    int t = blockIdx.x * 256 + threadIdx.x;   // 1024*512
    int n = t / 512, k = t % 512;
    float v = w5[(size_t)k * 1024 + n];
    u16 h = bfhi(v);
    Bth[t] = h; Btl[t] = bflo(v, h);
}

// ---------------- split-bf16 MFMA GEMM, 128x128 tile, 4 waves (2x2) ----------------
// grid (Mtiles, Ntiles): m0 = blockIdx.x*128, n0 = blockIdx.y*128
// EPI=0: out[m][n] = acc + ep[n]
// EPI=1: colmax over 128 rows, +ep[n], leaky -> out[blockIdx.x*ldo + n]
template <int EPI>
__launch_bounds__(256, 2)
__global__ void mfma_gemm(const u16* __restrict__ Ah, const u16* __restrict__ Al,
                          long long aZ, int lda,
                          const u16* __restrict__ Bh, const u16* __restrict__ Bl,
                          long long bZ, int ldb,
                          const float* __restrict__ ep, long long epZ,
                          float* __restrict__ out, long long outZ, int ldo,
                          int K) {
    __shared__ u16 AsH[128][72], AsL[128][72], BsH[128][72], BsL[128][72];
    __shared__ float red[2][128];
    int tid = threadIdx.x;
    int m0 = blockIdx.x * 128, n0 = blockIdx.y * 128;
    int z = blockIdx.z;
    const u16* ah = Ah + (size_t)z * aZ;
    const u16* al = Al + (size_t)z * aZ;
    const u16* bh = Bh + (size_t)z * bZ;
    const u16* bl = Bl + (size_t)z * bZ;
    const float* epz = ep + (size_t)z * epZ;
    float* op = out + (size_t)z * outZ;

    int wid = tid >> 6, lane = tid & 63;
    int wm = wid >> 1, wn = wid & 1;
    int l15 = lane & 15, l4 = lane >> 4;
    int srow = tid >> 1;
    int skc0 = (tid & 1) * 4;

    f32x4 acc[4][4];
#pragma unroll
    for (int i = 0; i < 4; ++i)
#pragma unroll
        for (int j = 0; j < 4; ++j) acc[i][j] = (f32x4){0.f, 0.f, 0.f, 0.f};

    for (int k0 = 0; k0 < K; k0 += 64) {
        if (k0) __syncthreads();
        {
            const u16* ga  = ah + (size_t)(m0 + srow) * lda + k0 + skc0 * 8;
            const u16* gal = al + (size_t)(m0 + srow) * lda + k0 + skc0 * 8;
            const u16* gb  = bh + (size_t)(n0 + srow) * ldb + k0 + skc0 * 8;
            const u16* gbl = bl + (size_t)(n0 + srow) * ldb + k0 + skc0 * 8;
            uint4* wa  = (uint4*)&AsH[srow][skc0 * 8];
            uint4* wal = (uint4*)&AsL[srow][skc0 * 8];
            uint4* wb  = (uint4*)&BsH[srow][skc0 * 8];
            uint4* wbl = (uint4*)&BsL[srow][skc0 * 8];
#pragma unroll
            for (int c = 0; c < 4; ++c) {
                wa[c]  = *(const uint4*)(ga  + c * 8);
                wal[c] = *(const uint4*)(gal + c * 8);
                wb[c]  = *(const uint4*)(gb  + c * 8);
                wbl[c] = *(const uint4*)(gbl + c * 8);
            }
        }
        __syncthreads();
#pragma unroll
        for (int kk = 0; kk < 2; ++kk) {
            int ko = kk * 32 + l4 * 8;
            bf16x8 aH[4], aL[4], bH[4], bL[4];
#pragma unroll
            for (int i = 0; i < 4; ++i) {
                int ra = wm * 64 + i * 16 + l15;
                aH[i] = *(const bf16x8*)&AsH[ra][ko];
                aL[i] = *(const bf16x8*)&AsL[ra][ko];
                int rb = wn * 64 + i * 16 + l15;
                bH[i] = *(const bf16x8*)&BsH[rb][ko];
                bL[i] = *(const bf16x8*)&BsL[rb][ko];
            }
#pragma unroll
            for (int i = 0; i < 4; ++i)
#pragma unroll
                for (int j = 0; j < 4; ++j) {
                    acc[i][j] = __builtin_amdgcn_mfma_f32_16x16x32_bf16(aH[i], bH[j], acc[i][j], 0, 0, 0);
                    acc[i][j] = __builtin_amdgcn_mfma_f32_16x16x32_bf16(aH[i], bL[j], acc[i][j], 0, 0, 0);
                    acc[i][j] = __builtin_amdgcn_mfma_f32_16x16x32_bf16(aL[i], bH[j], acc[i][j], 0, 0, 0);
                }
        }
    }

    if (EPI == 0) {
#pragma unroll
        for (int i = 0; i < 4; ++i)
#pragma unroll
            for (int r = 0; r < 4; ++r) {
                int grow = m0 + wm * 64 + i * 16 + l4 * 4 + r;
#pragma unroll
                for (int j = 0; j < 4; ++j) {
                    int col = n0 + wn * 64 + j * 16 + l15;
                    op[(size_t)grow * ldo + col] = acc[i][j][r] + epz[col];
                }
            }
    } else {
        float pm[4];
#pragma unroll
        for (int j = 0; j < 4; ++j) {
            float v = -FLT_MAX;
#pragma unroll
            for (int i = 0; i < 4; ++i)
#pragma unroll
                for (int r = 0; r < 4; ++r) v = fmaxf(v, acc[i][j][r]);
            v = fmaxf(v, __shfl_xor(v, 16));
            v = fmaxf(v, __shfl_xor(v, 32));
            pm[j] = v;
        }
        if (l4 == 0) {
#pragma unroll
            for (int j = 0; j < 4; ++j) red[wm][wn * 64 + j * 16 + l15] = pm[j];
        }
        __syncthreads();
        if (tid < 128) {
            float v = fmaxf(red[0][tid], red[1][tid]) + epz[n0 + tid];
            v = (v > 0.f) ? v : 0.2f * v;
            op[(size_t)blockIdx.x * ldo + n0 + tid] = v;
        }
    }
}

// ---------------- fp32 fallback GEMM (conv1 only, K=3) ----------------
template <int EPI>
__launch_bounds__(256)
__global__ void gemm_kernel(const float* __restrict__ A, int lda,
                            const float* __restrict__ B, const float* __restrict__ bias,
                            float* __restrict__ out, int M, int K, int N) {
    __shared__ __align__(16) float As[16][68];
    __shared__ __align__(16) float Bs[16][68];
    int tid = threadIdx.x;
    int m0 = blockIdx.x * 64, n0 = blockIdx.y * 64;
    int tm = tid >> 4, tn = tid & 15;
    float acc[4][4] = {{0.f}};
    for (int k0 = 0; k0 < K; k0 += 16) {
        {
            int m = tid >> 2;
            int kb = (tid & 3) * 4;
            const float* ar = A + (size_t)(m0 + m) * lda + k0 + kb;
#pragma unroll
            for (int e = 0; e < 4; e++) {
                int k = k0 + kb + e;
                As[kb + e][m] = (k < K) ? ar[e] : 0.f;
            }
            int kk = tid >> 4;
            int nb = (tid & 15) * 4;
            int kg = k0 + kk;
            const float* br = B + (size_t)kg * N + n0 + nb;
#pragma unroll
            for (int e = 0; e < 4; e++) Bs[kk][nb + e] = (kg < K) ? br[e] : 0.f;
        }
        __syncthreads();
#pragma unroll
        for (int kk = 0; kk < 16; ++kk) {
            float4 av = *(const float4*)&As[kk][tm * 4];
            float4 bv = *(const float4*)&Bs[kk][tn * 4];
            float a_[4] = {av.x, av.y, av.z, av.w};
            float b_[4] = {bv.x, bv.y, bv.z, bv.w};
#pragma unroll
            for (int i = 0; i < 4; i++)
#pragma unroll
                for (int j = 0; j < 4; j++)
                    acc[i][j] = fmaf(a_[i], b_[j], acc[i][j]);
        }
        __syncthreads();
    }
#pragma unroll
    for (int i = 0; i < 4; i++) {
        int m = m0 + tm * 4 + i;
        float* o = out + (size_t)m * N + n0 + tn * 4;
#pragma unroll
        for (int j = 0; j < 4; j++) o[j] = acc[i][j] + bias[n0 + tn * 4 + j];
    }
}

// ---------------- gather + leaky + max over k, writes split cat ----------------
template <int COUT>
__global__ void gather_max_kernel(const float* __restrict__ ut,
                                  const int* __restrict__ idx,
                                  u16* __restrict__ cathi, u16* __restrict__ catlo,
                                  int coloff) {
    const int P = 256 / COUT;
    int tid = threadIdx.x;
    int p = tid / COUT, d = tid % COUT;
    int pt = blockIdx.x * P + p;
    int b = pt >> 11, n = pt & 2047;
    __shared__ int sidx[P][KNN];
    for (int i = tid; i < P * KNN; i += 256) {
        int pp = i / KNN, kk = i % KNN;
        sidx[pp][kk] = idx[(size_t)(blockIdx.x * P + pp) * KNN + kk];
    }
    __syncthreads();
    const int N2 = 2 * COUT;
    const float* utb = ut + (size_t)b * N_ * N2;
    float tval = utb[(size_t)n * N2 + COUT + d];
    float acc = -FLT_MAX;
#pragma unroll 4
    for (int k = 0; k < KNN; k++) {
        int j = sidx[p][k];
        float s = utb[(size_t)j * N2 + d] + tval;
        s = (s > 0.f) ? s : 0.2f * s;
        acc = fmaxf(acc, s);
    }
    u16 h = bfhi(acc);
    cathi[(size_t)pt * 512 + coloff + d] = h;
    catlo[(size_t)pt * 512 + coloff + d] = bflo(acc, h);
}

// ---------------- feat = max over 16 row-blocks of gpart ----------------
__global__ void featmax_kernel(const float* __restrict__ gpart, float* __restrict__ feat) {
    int t = blockIdx.x * 256 + threadIdx.x;   // 16*1024
    int b = t >> 10, d = t & 1023;
    float m = -FLT_MAX;
    for (int rb = 0; rb < 16; ++rb)
        m = fmaxf(m, gpart[(size_t)(b * 16 + rb) * 1024 + d]);
    feat[t] = m;
}

// ---------------- small FC ----------------
__global__ void fc_kernel(const float* __restrict__ in, const float* __restrict__ W,
                          const float* __restrict__ bias, float* __restrict__ out,
                          int N, int act) {
    __shared__ float sin_[1024];
    __shared__ float red[4][64];
    int b = blockIdx.x;
    int lane = threadIdx.x & 63;
    int col = blockIdx.y * 64 + lane;
    int g = threadIdx.x >> 6;
    for (int i = threadIdx.x; i < 1024; i += 256) sin_[i] = in[b * 1024 + i];
    __syncthreads();
    float s = 0.f;
    int k0 = g * 256;
    for (int k = k0; k < k0 + 256; ++k) s = fmaf(sin_[k], W[(size_t)k * N + col], s);
    red[g][lane] = s;
    __syncthreads();
    if (g == 0) {
        float v = red[0][lane] + red[1][lane] + red[2][lane] + red[3][lane] + bias[col];
        if (act) v = fmaxf(v, 0.f);
        out[(size_t)b * N + col] = v;
    }
}

// ---------------- chamfer pass A ----------------
__launch_bounds__(256)
__global__ void chamferA_kernel(const float* __restrict__ coarse,
                                const float* __restrict__ pts,
                                float* __restrict__ pA) {
    __shared__ float spx[2048], spy[2048], spz[2048];
    __shared__ float red[4];
    int b = blockIdx.x, ch = blockIdx.y, tid = threadIdx.x;
    const float* pb = pts + (size_t)b * 6144;
    for (int i = tid; i < 2048; i += 256) {
        spx[i] = pb[i * 3]; spy[i] = pb[i * 3 + 1]; spz[i] = pb[i * 3 + 2];
    }
    __syncthreads();
    int q = ch * 32 + (tid >> 3);
    int oct = tid & 7;
    const float* cp = coarse + (size_t)b * 3072 + q * 3;
    float cx = cp[0], cy = cp[1], cz = cp[2];
    float mn0 = FLT_MAX, mn1 = FLT_MAX, mn2 = FLT_MAX, mn3 = FLT_MAX;
    int n0 = oct * 256;
    for (int n = n0; n < n0 + 256; n += 4) {
        float dx, dy, dz;
        dx = cx - spx[n];     dy = cy - spy[n];     dz = cz - spz[n];
        mn0 = fminf(mn0, fmaf(dx, dx, fmaf(dy, dy, dz * dz)));
        dx = cx - spx[n + 1]; dy = cy - spy[n + 1]; dz = cz - spz[n + 1];
        mn1 = fminf(mn1, fmaf(dx, dx, fmaf(dy, dy, dz * dz)));
        dx = cx - spx[n + 2]; dy = cy - spy[n + 2]; dz = cz - spz[n + 2];
        mn2 = fminf(mn2, fmaf(dx, dx, fmaf(dy, dy, dz * dz)));
        dx = cx - spx[n + 3]; dy = cy - spy[n + 3]; dz = cz - spz[n + 3];
        mn3 = fminf(mn3, fmaf(dx, dx, fmaf(dy, dy, dz * dz)));
    }
    float mn = fminf(fminf(mn0, mn1), fminf(mn2, mn3));
    mn = fminf(mn, __shfl_xor(mn, 1));
    mn = fminf(mn, __shfl_xor(mn, 2));
    mn = fminf(mn, __shfl_xor(mn, 4));
    float s = (oct == 0) ? mn : 0.f;
#pragma unroll
    for (int off = 32; off > 0; off >>= 1) s += __shfl_down(s, off);
    int w = tid >> 6, lane = tid & 63;
    if (lane == 0) red[w] = s;
    __syncthreads();
    if (tid == 0) pA[b * 32 + ch] = red[0] + red[1] + red[2] + red[3];
}

// ---------------- chamfer pass B ----------------
__launch_bounds__(256)
__global__ void chamferB_kernel(const float* __restrict__ coarse,
                                const float* __restrict__ pts,
                                float* __restrict__ pB) {
    __shared__ float scx[1024], scy[1024], scz[1024];
    __shared__ float red[4];
    int b = blockIdx.x, ch = blockIdx.y, tid = threadIdx.x;
    const float* cb = coarse + (size_t)b * 3072;
    for (int i = tid; i < 1024; i += 256) {
        scx[i] = cb[i * 3]; scy[i] = cb[i * 3 + 1]; scz[i] = cb[i * 3 + 2];
    }
    __syncthreads();
    int p = ch * 64 + (tid >> 2);
    int quad = tid & 3;
    const float* pp = pts + (size_t)b * 6144 + p * 3;
    float px = pp[0], py = pp[1], pz = pp[2];
    float mn0 = FLT_MAX, mn1 = FLT_MAX, mn2 = FLT_MAX, mn3 = FLT_MAX;
    int m0 = quad * 256;
    for (int m = m0; m < m0 + 256; m += 4) {
        float dx, dy, dz;
        dx = px - scx[m];     dy = py - scy[m];     dz = pz - scz[m];
        mn0 = fminf(mn0, fmaf(dx, dx, fmaf(dy, dy, dz * dz)));
        dx = px - scx[m + 1]; dy = py - scy[m + 1]; dz = pz - scz[m + 1];
        mn1 = fminf(mn1, fmaf(dx, dx, fmaf(dy, dy, dz * dz)));
        dx = px - scx[m + 2]; dy = py - scy[m + 2]; dz = pz - scz[m + 2];
        mn2 = fminf(mn2, fmaf(dx, dx, fmaf(dy, dy, dz * dz)));
        dx = px - scx[m + 3]; dy = py - scy[m + 3]; dz = pz - scz[m + 3];
        mn3 = fminf(mn3, fmaf(dx, dx, fmaf(dy, dy, dz * dz)));
    }
    float mn = fminf(fminf(mn0, mn1), fminf(mn2, mn3));
    mn = fminf(mn, __shfl_xor(mn, 1));
    mn = fminf(mn, __shfl_xor(mn, 2));
    float s = (quad == 0) ? mn : 0.f;
#pragma unroll
    for (int off = 32; off > 0; off >>= 1) s += __shfl_down(s, off);
    int w = tid >> 6, lane = tid & 63;
    if (lane == 0) red[w] = s;
    __syncthreads();
    if (tid == 0) pB[b * 32 + ch] = red[0] + red[1] + red[2] + red[3];
}

__global__ void loss_kernel(const float* __restrict__ pA, const float* __restrict__ pB,
                            float* __restrict__ out) {
    __shared__ float rA[4], rB[4];
    int tid = threadIdx.x;   // 256
    float a = pA[tid] + pA[tid + 256];
    float b = pB[tid] + pB[tid + 256];
#pragma unroll
    for (int off = 32; off > 0; off >>= 1) {
        a += __shfl_down(a, off);
        b += __shfl_down(b, off);
    }
    int w = tid >> 6, lane = tid & 63;
    if (lane == 0) { rA[w] = a; rB[w] = b; }
    __syncthreads();
    if (tid == 0)
        out[0] = (rA[0] + rA[1] + rA[2] + rA[3]) / (16.f * 1024.f)
               + (rB[0] + rB[1] + rB[2] + rB[3]) / (16.f * 2048.f);
}

extern "C" void kernel_launch(void* const* d_in, const int* in_sizes, int n_in,
                              void* d_out, int out_size, void* d_ws, size_t ws_size,
                              hipStream_t stream) {
    const float* corrupted = (const float*)d_in[0];
    const float* pts = (const float*)d_in[1];
    const float* w1 = (const float*)d_in[2];   const float* b1 = (const float*)d_in[3];
    const float* w2 = (const float*)d_in[4];   const float* b2 = (const float*)d_in[5];
    const float* w3 = (const float*)d_in[6];   const float* b3 = (const float*)d_in[7];
    const float* w4 = (const float*)d_in[8];   const float* b4 = (const float*)d_in[9];
    const float* w5 = (const float*)d_in[10];  const float* b5 = (const float*)d_in[11];
    const float* fw1 = (const float*)d_in[12]; const float* fb1 = (const float*)d_in[13];
    const float* fw2 = (const float*)d_in[14]; const float* fb2 = (const float*)d_in[15];
    const float* fw3 = (const float*)d_in[16]; const float* fb3 = (const float*)d_in[17];
    float* out = (float*)d_out;

    char* ws = (char*)d_ws;
    u16*   cathi  = (u16*)(ws);                   // [32768][512] bf16 hi   32 MB
    u16*   catlo  = (u16*)(ws + 33554432);        // [32768][512] bf16 lo   32 MB
    float* ut     = (float*)(ws + 67108864);      // [32768][<=512] f32     64 MB
    int*   idx    = (int*)  (ws + 134217728);     // [32768][20]
    float* sqn    = (float*)(ws + 136839168);     // [32768]
    u16*   Bth    = (u16*)(ws + 136970240);       // [<=1024][<=512] bf16   1 MB
    u16*   Btl    = (u16*)(ws + 138018816);       // 1 MB
    float* bt     = (float*)(ws + 139067392);     // [<=1024]
    float* gpart  = (float*)(ws + 139071488);     // [256][1024]            1 MB
    float* feat   = (float*)(ws + 140120064);     // [16][1024]
    float* h1     = (float*)(ws + 140185600);
    float* h2     = (float*)(ws + 140251136);
    float* coarse = (float*)(ws + 140316672);     // [16][3072]
    float* pA     = (float*)(ws + 140513280);     // [512]
    float* pB     = (float*)(ws + 140515328);     // [512]
    float* wtf    = (float*)Bth;                  // conv1 fp32 wt alias

    // ---- conv1: C=3 (direct-coord knn, fp32 tiny GEMM) ----
    select3_kernel<<<8192, 256, 0, stream>>>(corrupted, idx);
    wt_kernel<<<2, 256, 0, stream>>>(w1, b1, wtf, bt, 3, 64);
    gemm_kernel<0><<<dim3(512, 2), 256, 0, stream>>>(corrupted, 3, wtf, bt, ut, B_ * N_, 3, 128);
    gather_max_kernel<64><<<8192, 256, 0, stream>>>(ut, idx, cathi, catlo, 0);

    // ---- convs 2-4: fused MFMA knn + MFMA edge GEMM + gather ----
    auto conv = [&](int coloff, int C, int Cout, const float* w, const float* bias, int colout) {
        int N2 = 2 * Cout;
        sqnorm_split_kernel<<<128, 256, 0, stream>>>(cathi, catlo, coloff, C, sqn);
        if (C == 64)
            knn_fused_kernel<64><<<dim3(64, 16), 256, 0, stream>>>(cathi, catlo, coloff, sqn, idx);
        else
            knn_fused_kernel<128><<<dim3(64, 16), 256, 0, stream>>>(cathi, catlo, coloff, sqn, idx);
        prep_edge_B<<<(N2 * C + 255) / 256, 256, 0, stream>>>(w, bias, Bth, Btl, bt, C, Cout);
        mfma_gemm<0><<<dim3(256, N2 / 128), 256, 0, stream>>>(
            cathi + coloff, catlo + coloff, 0, 512,
            Bth, Btl, 0, C,
            bt, 0,
            ut, 0, N2, C);
        if (Cout == 64)       gather_max_kernel<64><<<8192, 256, 0, stream>>>(ut, idx, cathi, catlo, colout);
        else if (Cout == 128) gather_max_kernel<128><<<16384, 256, 0, stream>>>(ut, idx, cathi, catlo, colout);
        else                  gather_max_kernel<256><<<32768, 256, 0, stream>>>(ut, idx, cathi, catlo, colout);
    };
    conv(0, 64, 64, w2, b2, 64);
    conv(64, 64, 128, w3, b3, 128);
    conv(128, 128, 256, w4, b4, 256);

    // ---- w5 + leaky + max over N (fused epilogue) ----
    prep_w5_kernel<<<2048, 256, 0, stream>>>(w5, Bth, Btl);
    mfma_gemm<1><<<dim3(256, 8), 256, 0, stream>>>(
        cathi, catlo, 0, 512,
        Bth, Btl, 0, 512,
        b5, 0,
        gpart, 0, 1024, 512);
    featmax_kernel<<<64, 256, 0, stream>>>(gpart, feat);

    fc_kernel<<<dim3(16, 16), 256, 0, stream>>>(feat, fw1, fb1, h1, 1024, 1);
    fc_kernel<<<dim3(16, 16), 256, 0, stream>>>(h1, fw2, fb2, h2, 1024, 1);
    fc_kernel<<<dim3(16, 48), 256, 0, stream>>>(h2, fw3, fb3, coarse, 3072, 0);

    chamferA_kernel<<<dim3(16, 32), 256, 0, stream>>>(coarse, pts, pA);
    chamferB_kernel<<<dim3(16, 32), 256, 0, stream>>>(coarse, pts, pB);
    loss_kernel<<<1, 256, 0, stream>>>(pA, pB, out);
}

// Round 7
// 1054.211 us; speedup vs baseline: 2.8369x; 2.8369x over previous
//
#include <hip/hip_runtime.h>
#include <float.h>

#define B_ 16
#define N_ 2048
#define KNN 20

typedef unsigned short u16;
typedef __attribute__((ext_vector_type(8))) short bf16x8;
typedef __attribute__((ext_vector_type(4))) float f32x4;

__device__ inline u16 bfhi(float v) {
    union { float f; unsigned u; } x; x.f = v;
    unsigned r = x.u + 0x7FFFu + ((x.u >> 16) & 1u);
    return (u16)(r >> 16);
}
__device__ inline u16 bflo(float v, u16 h) {
    union { unsigned u; float f; } y; y.u = ((unsigned)h) << 16;
    return bfhi(v - y.f);
}
__device__ inline unsigned fkey(float v) {
    union { float f; unsigned u; } x;
    x.f = fmaxf(v, 0.f);
    return x.u & 0x7FFFFFFFu;
}
__device__ inline unsigned umin_(unsigned a, unsigned b) { return a < b ? a : b; }

// ---------------- bitonic sort across 64 lanes (ascending by key) ----------------
template <bool P>
__device__ inline void bitonic64(unsigned& key, unsigned& pay, int lane) {
#pragma unroll
    for (int k = 2; k <= 64; k <<= 1) {
#pragma unroll
        for (int j = k >> 1; j > 0; j >>= 1) {
            unsigned ok = __shfl_xor(key, j);
            unsigned op = P ? __shfl_xor(pay, j) : 0u;
            bool up = ((lane & k) == 0);
            bool lower = ((lane & j) == 0);
            bool takeOther = (up == lower) ? (ok < key) : (ok > key);
            if (takeOther) { key = ok; if (P) pay = op; }
        }
    }
}

// ---------------- exact top-20-smallest via threshold filter ----------------
__device__ inline void select20(const unsigned* kr, int lane,
                                unsigned* klist, unsigned* ilist,
                                int* __restrict__ outIdx) {
    unsigned lm = kr[0];
#pragma unroll
    for (int i = 1; i < 32; ++i) lm = umin_(lm, kr[i]);
    unsigned dummy = 0, sk = lm;
    bitonic64<false>(sk, dummy, lane);
    unsigned S = __shfl(sk, 19);
    unsigned c = 0;
#pragma unroll
    for (int i = 0; i < 32; ++i) c += (kr[i] <= S) ? 1u : 0u;
    unsigned incl = c;
#pragma unroll
    for (int d = 1; d < 64; d <<= 1) {
        unsigned t = __shfl_up(incl, d);
        if (lane >= d) incl += t;
    }
    unsigned stot = __shfl(incl, 63);
    unsigned pos = incl - c;
    klist[lane] = 0xFFFFFFFFu;
    __syncthreads();
#pragma unroll
    for (int i = 0; i < 32; ++i) {
        if (kr[i] <= S) {
            if (pos < 64u) {
                klist[pos] = kr[i];
                ilist[pos] = ((unsigned)(i >> 2) << 8) + (unsigned)lane * 4u + (unsigned)(i & 3);
            }
            ++pos;
        }
    }
    __syncthreads();
    if (stot <= 64u) {
        unsigned key = klist[lane], pay = ilist[lane];
        bitonic64<true>(key, pay, lane);
        if (lane < KNN) outIdx[lane] = (int)pay;
    } else {
        unsigned taken = 0;
        for (int it = 0; it < KNN; ++it) {
            unsigned bk = 0xFFFFFFFFu; int bi = 0;
#pragma unroll
            for (int i = 0; i < 32; ++i) {
                bool better = (((taken >> i) & 1u) == 0u) && (kr[i] < bk);
                if (better) { bk = kr[i]; bi = i; }
            }
            unsigned bl = (unsigned)lane;
#pragma unroll
            for (int off = 32; off > 0; off >>= 1) {
                unsigned ok = __shfl_down(bk, off);
                unsigned ol = __shfl_down(bl, off);
                int oi = __shfl_down(bi, off);
                if (ok < bk) { bk = ok; bl = ol; bi = oi; }
            }
            bl = __shfl(bl, 0); bi = __shfl(bi, 0);
            if (lane == (int)bl) taken |= (1u << bi);
            if (lane == 0) outIdx[it] = (int)(((unsigned)(bi >> 2) << 8) + bl * 4u + (unsigned)(bi & 3));
        }
    }
}

// ---------------- sq-norms from split cat ----------------
__global__ void sqnorm_split_kernel(const u16* __restrict__ hi, const u16* __restrict__ lo,
                                    int coloff, int C, float* __restrict__ sqn) {
    int t = blockIdx.x * 256 + threadIdx.x;
    if (t >= B_ * N_) return;
    const u16* rh = hi + (size_t)t * 512 + coloff;
    const u16* rl = lo + (size_t)t * 512 + coloff;
    float s = 0.f;
    for (int c = 0; c < C; ++c) {
        union { unsigned u; float f; } a, b;
        a.u = ((unsigned)rh[c]) << 16;
        b.u = ((unsigned)rl[c]) << 16;
        float v = a.f + b.f;
        s = fmaf(v, v, s);
    }
    sqn[t] = s;
}

// select for convs 2-4: reads precomputed dist rows
__launch_bounds__(256)
__global__ void select_kernel(const float* __restrict__ dist, int* __restrict__ idx_out) {
    __shared__ unsigned kl[4][64], il[4][64];
    int tid = threadIdx.x, w = tid >> 6, lane = tid & 63;
    size_t q = (size_t)blockIdx.x * 4 + w;
    const float* src = dist + q * N_;
    unsigned kr[32];
#pragma unroll
    for (int j = 0; j < 8; ++j) {
        float4 v = *(const float4*)&src[j * 256 + lane * 4];
        kr[j * 4 + 0] = fkey(v.x);
        kr[j * 4 + 1] = fkey(v.y);
        kr[j * 4 + 2] = fkey(v.z);
        kr[j * 4 + 3] = fkey(v.w);
    }
    select20(kr, lane, kl[w], il[w], idx_out + q * KNN);
}

// select for conv1: distances straight from 3-D coords
__launch_bounds__(256)
__global__ void select3_kernel(const float* __restrict__ x, int* __restrict__ idx_out) {
    __shared__ __align__(16) float cx[N_], cy[N_], cz[N_];
    __shared__ unsigned kl[4][64], il[4][64];
    int tid = threadIdx.x, blk = blockIdx.x;
    int b = blk >> 9, n0 = (blk & 511) * 4;
    for (int i = tid; i < N_; i += 256) {
        const float* p = x + (size_t)(b * N_ + i) * 3;
        cx[i] = p[0]; cy[i] = p[1]; cz[i] = p[2];
    }
    __syncthreads();
    int w = tid >> 6, lane = tid & 63;
    int q = n0 + w;
    float qx = cx[q], qy = cy[q], qz = cz[q];
    unsigned kr[32];
#pragma unroll
    for (int j = 0; j < 8; ++j) {
        float4 vx = *(const float4*)&cx[j * 256 + lane * 4];
        float4 vy = *(const float4*)&cy[j * 256 + lane * 4];
        float4 vz = *(const float4*)&cz[j * 256 + lane * 4];
        float dx, dy, dz;
        dx = qx - vx.x; dy = qy - vy.x; dz = qz - vz.x;
        kr[j * 4 + 0] = fkey(fmaf(dx, dx, fmaf(dy, dy, dz * dz)));
        dx = qx - vx.y; dy = qy - vy.y; dz = qz - vz.y;
        kr[j * 4 + 1] = fkey(fmaf(dx, dx, fmaf(dy, dy, dz * dz)));
        dx = qx - vx.z; dy = qy - vy.z; dz = qz - vz.z;
        kr[j * 4 + 2] = fkey(fmaf(dx, dx, fmaf(dy, dy, dz * dz)));
        dx = qx - vx.w; dy = qy - vy.w; dz = qz - vz.w;
        kr[j * 4 + 3] = fkey(fmaf(dx, dx, fmaf(dy, dy, dz * dz)));
    }
    select20(kr, lane, kl[w], il[w], idx_out + ((size_t)(b * N_ + q)) * KNN);
}

// ---------------- weight prep ----------------
__global__ void wt_kernel(const float* __restrict__ w, const float* __restrict__ b,
                          float* __restrict__ wt, float* __restrict__ bt,
                          int C, int Cout) {
    int N2 = 2 * Cout;
    int t = blockIdx.x * 256 + threadIdx.x;
    if (t < C * N2) {
        int c = t / N2, d = t % N2;
        float v;
        if (d < Cout) v = w[c * Cout + d];
        else          v = w[(C + c) * Cout + (d - Cout)] - w[c * Cout + (d - Cout)];
        wt[t] = v;
    }
    if (t < N2) bt[t] = (t < Cout) ? 0.f : b[t - Cout];
}

__global__ void prep_edge_B(const float* __restrict__ w, const float* __restrict__ b,
                            u16* __restrict__ Bth, u16* __restrict__ Btl,
                            float* __restrict__ bt, int C, int Cout) {
    int N2 = 2 * Cout;
    int t = blockIdx.x * 256 + threadIdx.x;
    if (t < N2 * C) {
        int d = t / C, c = t % C;
        float v = (d < Cout) ? w[c * Cout + d]
                             : (w[(C + c) * Cout + (d - Cout)] - w[c * Cout + (d - Cout)]);
        u16 h = bfhi(v);
        Bth[t] = h; Btl[t] = bflo(v, h);
    }
    if (t < N2) bt[t] = (t < Cout) ? 0.f : b[t - Cout];
}

__global__ void prep_w5_kernel(const float* __restrict__ w5,
                               u16* __restrict__ Bth, u16* __restrict__ Btl) {
    int t = blockIdx.x * 256 + threadIdx.x;   // 1024*512
    int n = t / 512, k = t % 512;
    float v = w5[(size_t)k * 1024 + n];
    u16 h = bfhi(v);
    Bth[t] = h; Btl[t] = bflo(v, h);
}

// ---------------- split-bf16 MFMA GEMM, 128x128 tile, 4 waves (2x2) ----------------
// EPI=0: out[m][n] = acc + ep[n]; grid (Mtiles, Ntiles): m0=bx*128, n0=by*128
// EPI=1: colmax over 128 rows, +ep[n], leaky -> out[blockIdx.x*ldo + n]
// EPI=2: SYMMETRIC dist (A==B): grid (136, 1, z); upper-triangle tile (bi<=bj),
//        writes tile + LDS-transposed mirror. out[m][n] = ep[m]+ep[n]-2*acc.
template <int EPI>
__launch_bounds__(256, 2)
__global__ void mfma_gemm(const u16* __restrict__ Ah, const u16* __restrict__ Al,
                          long long aZ, int lda,
                          const u16* __restrict__ Bh, const u16* __restrict__ Bl,
                          long long bZ, int ldb,
                          const float* __restrict__ ep, long long epZ,
                          float* __restrict__ out, long long outZ, int ldo,
                          int K) {
    __shared__ __align__(16) char smem[73728];
    u16 (*AsH)[72] = (u16(*)[72])(smem);
    u16 (*AsL)[72] = (u16(*)[72])(smem + 18432);
    u16 (*BsH)[72] = (u16(*)[72])(smem + 36864);
    u16 (*BsL)[72] = (u16(*)[72])(smem + 55296);
    float (*LT)[136] = (float(*)[136])(smem);   // alias, used post-loop (EPI=2)
    __shared__ float red[2][128];
    int tid = threadIdx.x;
    int m0, n0;
    if (EPI == 2) {
        int t = blockIdx.x, rem = 16, bi = 0;
        while (t >= rem) { t -= rem; ++bi; --rem; }
        m0 = bi * 128; n0 = (bi + t) * 128;
    } else {
        m0 = blockIdx.x * 128; n0 = blockIdx.y * 128;
    }
    int z = blockIdx.z;
    const u16* ah = Ah + (size_t)z * aZ;
    const u16* al = Al + (size_t)z * aZ;
    const u16* bh = Bh + (size_t)z * bZ;
    const u16* bl = Bl + (size_t)z * bZ;
    const float* epz = ep + (size_t)z * epZ;
    float* op = out + (size_t)z * outZ;

    int wid = tid >> 6, lane = tid & 63;
    int wm = wid >> 1, wn = wid & 1;
    int l15 = lane & 15, l4 = lane >> 4;
    int srow = tid >> 1;
    int skc0 = (tid & 1) * 4;

    f32x4 acc[4][4];
#pragma unroll
    for (int i = 0; i < 4; ++i)
#pragma unroll
        for (int j = 0; j < 4; ++j) acc[i][j] = (f32x4){0.f, 0.f, 0.f, 0.f};

    for (int k0 = 0; k0 < K; k0 += 64) {
        if (k0) __syncthreads();
        {
            const u16* ga  = ah + (size_t)(m0 + srow) * lda + k0 + skc0 * 8;
            const u16* gal = al + (size_t)(m0 + srow) * lda + k0 + skc0 * 8;
            const u16* gb  = bh + (size_t)(n0 + srow) * ldb + k0 + skc0 * 8;
            const u16* gbl = bl + (size_t)(n0 + srow) * ldb + k0 + skc0 * 8;
            uint4* wa  = (uint4*)&AsH[srow][skc0 * 8];
            uint4* wal = (uint4*)&AsL[srow][skc0 * 8];
            uint4* wb  = (uint4*)&BsH[srow][skc0 * 8];
            uint4* wbl = (uint4*)&BsL[srow][skc0 * 8];
#pragma unroll
            for (int c = 0; c < 4; ++c) {
                wa[c]  = *(const uint4*)(ga  + c * 8);
                wal[c] = *(const uint4*)(gal + c * 8);
                wb[c]  = *(const uint4*)(gb  + c * 8);
                wbl[c] = *(const uint4*)(gbl + c * 8);
            }
        }
        __syncthreads();
#pragma unroll
        for (int kk = 0; kk < 2; ++kk) {
            int ko = kk * 32 + l4 * 8;
            bf16x8 aH[4], aL[4], bH[4], bL[4];
#pragma unroll
            for (int i = 0; i < 4; ++i) {
                int ra = wm * 64 + i * 16 + l15;
                aH[i] = *(const bf16x8*)&AsH[ra][ko];
                aL[i] = *(const bf16x8*)&AsL[ra][ko];
                int rb = wn * 64 + i * 16 + l15;
                bH[i] = *(const bf16x8*)&BsH[rb][ko];
                bL[i] = *(const bf16x8*)&BsL[rb][ko];
            }
#pragma unroll
            for (int i = 0; i < 4; ++i)
#pragma unroll
                for (int j = 0; j < 4; ++j) {
                    acc[i][j] = __builtin_amdgcn_mfma_f32_16x16x32_bf16(aH[i], bH[j], acc[i][j], 0, 0, 0);
                    acc[i][j] = __builtin_amdgcn_mfma_f32_16x16x32_bf16(aH[i], bL[j], acc[i][j], 0, 0, 0);
                    acc[i][j] = __builtin_amdgcn_mfma_f32_16x16x32_bf16(aL[i], bH[j], acc[i][j], 0, 0, 0);
                }
        }
    }

    if (EPI == 0) {
#pragma unroll
        for (int i = 0; i < 4; ++i)
#pragma unroll
            for (int r = 0; r < 4; ++r) {
                int grow = m0 + wm * 64 + i * 16 + l4 * 4 + r;
#pragma unroll
                for (int j = 0; j < 4; ++j) {
                    int col = n0 + wn * 64 + j * 16 + l15;
                    op[(size_t)grow * ldo + col] = acc[i][j][r] + epz[col];
                }
            }
    } else if (EPI == 1) {
        float pm[4];
#pragma unroll
        for (int j = 0; j < 4; ++j) {
            float v = -FLT_MAX;
#pragma unroll
            for (int i = 0; i < 4; ++i)
#pragma unroll
                for (int r = 0; r < 4; ++r) v = fmaxf(v, acc[i][j][r]);
            v = fmaxf(v, __shfl_xor(v, 16));
            v = fmaxf(v, __shfl_xor(v, 32));
            pm[j] = v;
        }
        if (l4 == 0) {
#pragma unroll
            for (int j = 0; j < 4; ++j) red[wm][wn * 64 + j * 16 + l15] = pm[j];
        }
        __syncthreads();
        if (tid < 128) {
            float v = fmaxf(red[0][tid], red[1][tid]) + epz[n0 + tid];
            v = (v > 0.f) ? v : 0.2f * v;
            op[(size_t)blockIdx.x * ldo + n0 + tid] = v;
        }
    } else {
        // direct tile write
#pragma unroll
        for (int i = 0; i < 4; ++i)
#pragma unroll
            for (int r = 0; r < 4; ++r) {
                int grow = m0 + wm * 64 + i * 16 + l4 * 4 + r;
                float sm = epz[grow];
#pragma unroll
                for (int j = 0; j < 4; ++j) {
                    int col = n0 + wn * 64 + j * 16 + l15;
                    op[(size_t)grow * ldo + col] = sm + epz[col] - 2.f * acc[i][j][r];
                }
            }
        if (m0 != n0) {
            __syncthreads();   // staging LDS dead; safe to overwrite as LT
#pragma unroll
            for (int i = 0; i < 4; ++i)
#pragma unroll
                for (int j = 0; j < 4; ++j) {
                    int colL  = wn * 64 + j * 16 + l15;
                    int growL = wm * 64 + i * 16 + l4 * 4;
                    float4 v;
                    v.x = epz[m0 + growL + 0] + epz[n0 + colL] - 2.f * acc[i][j][0];
                    v.y = epz[m0 + growL + 1] + epz[n0 + colL] - 2.f * acc[i][j][1];
                    v.z = epz[m0 + growL + 2] + epz[n0 + colL] - 2.f * acc[i][j][2];
                    v.w = epz[m0 + growL + 3] + epz[n0 + colL] - 2.f * acc[i][j][3];
                    *(float4*)&LT[colL][growL] = v;
                }
            __syncthreads();
            // mirror tile: rows n0..n0+127, cols m0..m0+127, coalesced
            for (int rr0 = 0; rr0 < 128; rr0 += 8) {
                int rr = rr0 + (tid >> 5), cc = (tid & 31) * 4;
                float4 v = *(const float4*)&LT[rr][cc];
                *(float4*)&op[(size_t)(n0 + rr) * ldo + m0 + cc] = v;
            }
        }
    }
}

// ---------------- fp32 fallback GEMM (conv1 only, K=3) ----------------
template <int EPI>
__launch_bounds__(256)
__global__ void gemm_kernel(const float* __restrict__ A, int lda,
                            const float* __restrict__ B, const float* __restrict__ bias,
                            float* __restrict__ out, int M, int K, int N) {
    __shared__ __align__(16) float As[16][68];
    __shared__ __align__(16) float Bs[16][68];
    int tid = threadIdx.x;
    int m0 = blockIdx.x * 64, n0 = blockIdx.y * 64;
    int tm = tid >> 4, tn = tid & 15;
    float acc[4][4] = {{0.f}};
    for (int k0 = 0; k0 < K; k0 += 16) {
        {
            int m = tid >> 2;
            int kb = (tid & 3) * 4;
            const float* ar = A + (size_t)(m0 + m) * lda + k0 + kb;
#pragma unroll
            for (int e = 0; e < 4; e++) {
                int k = k0 + kb + e;
                As[kb + e][m] = (k < K) ? ar[e] : 0.f;
            }
            int kk = tid >> 4;
            int nb = (tid & 15) * 4;
            int kg = k0 + kk;
            const float* br = B + (size_t)kg * N + n0 + nb;
#pragma unroll
            for (int e = 0; e < 4; e++) Bs[kk][nb + e] = (kg < K) ? br[e] : 0.f;
        }
        __syncthreads();
#pragma unroll
        for (int kk = 0; kk < 16; ++kk) {
            float4 av = *(const float4*)&As[kk][tm * 4];
            float4 bv = *(const float4*)&Bs[kk][tn * 4];
            float a_[4] = {av.x, av.y, av.z, av.w};
            float b_[4] = {bv.x, bv.y, bv.z, bv.w};
#pragma unroll
            for (int i = 0; i < 4; i++)
#pragma unroll
                for (int j = 0; j < 4; j++)
                    acc[i][j] = fmaf(a_[i], b_[j], acc[i][j]);
        }
        __syncthreads();
    }
#pragma unroll
    for (int i = 0; i < 4; i++) {
        int m = m0 + tm * 4 + i;
        float* o = out + (size_t)m * N + n0 + tn * 4;
#pragma unroll
        for (int j = 0; j < 4; j++) o[j] = acc[i][j] + bias[n0 + tn * 4 + j];
    }
}

// ---------------- gather + leaky + max over k, writes split cat ----------------
template <int COUT>
__global__ void gather_max_kernel(const float* __restrict__ ut,
                                  const int* __restrict__ idx,
                                  u16* __restrict__ cathi, u16* __restrict__ catlo,
                                  int coloff) {
    const int P = 256 / COUT;
    int tid = threadIdx.x;
    int p = tid / COUT, d = tid % COUT;
    int pt = blockIdx.x * P + p;
    int b = pt >> 11, n = pt & 2047;
    __shared__ int sidx[P][KNN];
    for (int i = tid; i < P * KNN; i += 256) {
        int pp = i / KNN, kk = i % KNN;
        sidx[pp][kk] = idx[(size_t)(blockIdx.x * P + pp) * KNN + kk];
    }
    __syncthreads();
    const int N2 = 2 * COUT;
    const float* utb = ut + (size_t)b * N_ * N2;
    float tval = utb[(size_t)n * N2 + COUT + d];
    float acc = -FLT_MAX;
#pragma unroll 4
    for (int k = 0; k < KNN; k++) {
        int j = sidx[p][k];
        float s = utb[(size_t)j * N2 + d] + tval;
        s = (s > 0.f) ? s : 0.2f * s;
        acc = fmaxf(acc, s);
    }
    u16 h = bfhi(acc);
    cathi[(size_t)pt * 512 + coloff + d] = h;
    catlo[(size_t)pt * 512 + coloff + d] = bflo(acc, h);
}

// ---------------- feat = max over 16 row-blocks of gpart ----------------
__global__ void featmax_kernel(const float* __restrict__ gpart, float* __restrict__ feat) {
    int t = blockIdx.x * 256 + threadIdx.x;   // 16*1024
    int b = t >> 10, d = t & 1023;
    float m = -FLT_MAX;
    for (int rb = 0; rb < 16; ++rb)
        m = fmaxf(m, gpart[(size_t)(b * 16 + rb) * 1024 + d]);
    feat[t] = m;
}

// ---------------- small FC ----------------
__global__ void fc_kernel(const float* __restrict__ in, const float* __restrict__ W,
                          const float* __restrict__ bias, float* __restrict__ out,
                          int N, int act) {
    __shared__ float sin_[1024];
    __shared__ float red[4][64];
    int b = blockIdx.x;
    int lane = threadIdx.x & 63;
    int col = blockIdx.y * 64 + lane;
    int g = threadIdx.x >> 6;
    for (int i = threadIdx.x; i < 1024; i += 256) sin_[i] = in[b * 1024 + i];
    __syncthreads();
    float s = 0.f;
    int k0 = g * 256;
    for (int k = k0; k < k0 + 256; ++k) s = fmaf(sin_[k], W[(size_t)k * N + col], s);
    red[g][lane] = s;
    __syncthreads();
    if (g == 0) {
        float v = red[0][lane] + red[1][lane] + red[2][lane] + red[3][lane] + bias[col];
        if (act) v = fmaxf(v, 0.f);
        out[(size_t)b * N + col] = v;
    }
}

// ---------------- chamfer pass A ----------------
__launch_bounds__(256)
__global__ void chamferA_kernel(const float* __restrict__ coarse,
                                const float* __restrict__ pts,
                                float* __restrict__ pA) {
    __shared__ float spx[2048], spy[2048], spz[2048];
    __shared__ float red[4];
    int b = blockIdx.x, ch = blockIdx.y, tid = threadIdx.x;
    const float* pb = pts + (size_t)b * 6144;
    for (int i = tid; i < 2048; i += 256) {
        spx[i] = pb[i * 3]; spy[i] = pb[i * 3 + 1]; spz[i] = pb[i * 3 + 2];
    }
    __syncthreads();
    int q = ch * 32 + (tid >> 3);
    int oct = tid & 7;
    const float* cp = coarse + (size_t)b * 3072 + q * 3;
    float cx = cp[0], cy = cp[1], cz = cp[2];
    float mn0 = FLT_MAX, mn1 = FLT_MAX, mn2 = FLT_MAX, mn3 = FLT_MAX;
    int n0 = oct * 256;
    for (int n = n0; n < n0 + 256; n += 4) {
        float dx, dy, dz;
        dx = cx - spx[n];     dy = cy - spy[n];     dz = cz - spz[n];
        mn0 = fminf(mn0, fmaf(dx, dx, fmaf(dy, dy, dz * dz)));
        dx = cx - spx[n + 1]; dy = cy - spy[n + 1]; dz = cz - spz[n + 1];
        mn1 = fminf(mn1, fmaf(dx, dx, fmaf(dy, dy, dz * dz)));
        dx = cx - spx[n + 2]; dy = cy - spy[n + 2]; dz = cz - spz[n + 2];
        mn2 = fminf(mn2, fmaf(dx, dx, fmaf(dy, dy, dz * dz)));
        dx = cx - spx[n + 3]; dy = cy - spy[n + 3]; dz = cz - spz[n + 3];
        mn3 = fminf(mn3, fmaf(dx, dx, fmaf(dy, dy, dz * dz)));
    }
    float mn = fminf(fminf(mn0, mn1), fminf(mn2, mn3));
    mn = fminf(mn, __shfl_xor(mn, 1));
    mn = fminf(mn, __shfl_xor(mn, 2));
    mn = fminf(mn, __shfl_xor(mn, 4));
    float s = (oct == 0) ? mn : 0.f;
#pragma unroll
    for (int off = 32; off > 0; off >>= 1) s += __shfl_down(s, off);
    int w = tid >> 6, lane = tid & 63;
    if (lane == 0) red[w] = s;
    __syncthreads();
    if (tid == 0) pA[b * 32 + ch] = red[0] + red[1] + red[2] + red[3];
}

// ---------------- chamfer pass B ----------------
__launch_bounds__(256)
__global__ void chamferB_kernel(const float* __restrict__ coarse,
                                const float* __restrict__ pts,
                                float* __restrict__ pB) {
    __shared__ float scx[1024], scy[1024], scz[1024];
    __shared__ float red[4];
    int b = blockIdx.x, ch = blockIdx.y, tid = threadIdx.x;
    const float* cb = coarse + (size_t)b * 3072;
    for (int i = tid; i < 1024; i += 256) {
        scx[i] = cb[i * 3]; scy[i] = cb[i * 3 + 1]; scz[i] = cb[i * 3 + 2];
    }
    __syncthreads();
    int p = ch * 64 + (tid >> 2);
    int quad = tid & 3;
    const float* pp = pts + (size_t)b * 6144 + p * 3;
    float px = pp[0], py = pp[1], pz = pp[2];
    float mn0 = FLT_MAX, mn1 = FLT_MAX, mn2 = FLT_MAX, mn3 = FLT_MAX;
    int m0 = quad * 256;
    for (int m = m0; m < m0 + 256; m += 4) {
        float dx, dy, dz;
        dx = px - scx[m];     dy = py - scy[m];     dz = pz - scz[m];
        mn0 = fminf(mn0, fmaf(dx, dx, fmaf(dy, dy, dz * dz)));
        dx = px - scx[m + 1]; dy = py - scy[m + 1]; dz = pz - scz[m + 1];
        mn1 = fminf(mn1, fmaf(dx, dx, fmaf(dy, dy, dz * dz)));
        dx = px - scx[m + 2]; dy = py - scy[m + 2]; dz = pz - scz[m + 2];
        mn2 = fminf(mn2, fmaf(dx, dx, fmaf(dy, dy, dz * dz)));
        dx = px - scx[m + 3]; dy = py - scy[m + 3]; dz = pz - scz[m + 3];
        mn3 = fminf(mn3, fmaf(dx, dx, fmaf(dy, dy, dz * dz)));
    }
    float mn = fminf(fminf(mn0, mn1), fminf(mn2, mn3));
    mn = fminf(mn, __shfl_xor(mn, 1));
    mn = fminf(mn, __shfl_xor(mn, 2));
    float s = (quad == 0) ? mn : 0.f;
#pragma unroll
    for (int off = 32; off > 0; off >>= 1) s += __shfl_down(s, off);
    int w = tid >> 6, lane = tid & 63;
    if (lane == 0) red[w] = s;
    __syncthreads();
    if (tid == 0) pB[b * 32 + ch] = red[0] + red[1] + red[2] + red[3];
}

__global__ void loss_kernel(const float* __restrict__ pA, const float* __restrict__ pB,
                            float* __restrict__ out) {
    __shared__ float rA[4], rB[4];
    int tid = threadIdx.x;   // 256
    float a = pA[tid] + pA[tid + 256];
    float b = pB[tid] + pB[tid + 256];
#pragma unroll
    for (int off = 32; off > 0; off >>= 1) {
        a += __shfl_down(a, off);
        b += __shfl_down(b, off);
    }
    int w = tid >> 6, lane = tid & 63;
    if (lane == 0) { rA[w] = a; rB[w] = b; }
    __syncthreads();
    if (tid == 0)
        out[0] = (rA[0] + rA[1] + rA[2] + rA[3]) / (16.f * 1024.f)
               + (rB[0] + rB[1] + rB[2] + rB[3]) / (16.f * 2048.f);
}

extern "C" void kernel_launch(void* const* d_in, const int* in_sizes, int n_in,
                              void* d_out, int out_size, void* d_ws, size_t ws_size,
                              hipStream_t stream) {
    const float* corrupted = (const float*)d_in[0];
    const float* pts = (const float*)d_in[1];
    const float* w1 = (const float*)d_in[2];   const float* b1 = (const float*)d_in[3];
    const float* w2 = (const float*)d_in[4];   const float* b2 = (const float*)d_in[5];
    const float* w3 = (const float*)d_in[6];   const float* b3 = (const float*)d_in[7];
    const float* w4 = (const float*)d_in[8];   const float* b4 = (const float*)d_in[9];
    const float* w5 = (const float*)d_in[10];  const float* b5 = (const float*)d_in[11];
    const float* fw1 = (const float*)d_in[12]; const float* fb1 = (const float*)d_in[13];
    const float* fw2 = (const float*)d_in[14]; const float* fb2 = (const float*)d_in[15];
    const float* fw3 = (const float*)d_in[16]; const float* fb3 = (const float*)d_in[17];
    float* out = (float*)d_out;

    char* ws = (char*)d_ws;
    u16*   cathi  = (u16*)(ws);                   // [32768][512] bf16 hi   32 MB
    u16*   catlo  = (u16*)(ws + 33554432);        // [32768][512] bf16 lo   32 MB
    float* ut     = (float*)(ws + 67108864);      // [32768][<=512] f32     64 MB (aliased dist)
    float* dist   = ut;                           // [4][2048][2048] f32 per group
    int*   idx    = (int*)  (ws + 134217728);     // [32768][20]
    float* sqn    = (float*)(ws + 136839168);     // [32768]
    u16*   Bth    = (u16*)(ws + 136970240);       // [<=1024][<=512] bf16   1 MB
    u16*   Btl    = (u16*)(ws + 138018816);       // 1 MB
    float* bt     = (float*)(ws + 139067392);     // [<=1024]
    float* gpart  = (float*)(ws + 139071488);     // [256][1024]            1 MB
    float* feat   = (float*)(ws + 140120064);     // [16][1024]
    float* h1     = (float*)(ws + 140185600);
    float* h2     = (float*)(ws + 140251136);
    float* coarse = (float*)(ws + 140316672);     // [16][3072]
    float* pA     = (float*)(ws + 140513280);     // [512]
    float* pB     = (float*)(ws + 140515328);     // [512]
    float* wtf    = (float*)Bth;                  // conv1 fp32 wt alias

    // ---- conv1: C=3 (direct-coord knn, fp32 tiny GEMM) ----
    select3_kernel<<<8192, 256, 0, stream>>>(corrupted, idx);
    wt_kernel<<<2, 256, 0, stream>>>(w1, b1, wtf, bt, 3, 64);
    gemm_kernel<0><<<dim3(512, 2), 256, 0, stream>>>(corrupted, 3, wtf, bt, ut, B_ * N_, 3, 128);
    gather_max_kernel<64><<<8192, 256, 0, stream>>>(ut, idx, cathi, catlo, 0);

    // ---- convs 2-4: symmetric MFMA gram + select + MFMA edge GEMM + gather ----
    auto conv = [&](int coloff, int C, int Cout, const float* w, const float* bias, int colout) {
        int N2 = 2 * Cout;
        sqnorm_split_kernel<<<128, 256, 0, stream>>>(cathi, catlo, coloff, C, sqn);
        prep_edge_B<<<(N2 * C + 255) / 256, 256, 0, stream>>>(w, bias, Bth, Btl, bt, C, Cout);
        for (int g = 0; g < 4; ++g) {
            size_t off = ((size_t)g * 4 * N_) * 512 + coloff;
            mfma_gemm<2><<<dim3(136, 1, 4), 256, 0, stream>>>(
                cathi + off, catlo + off, (long long)N_ * 512, 512,
                cathi + off, catlo + off, (long long)N_ * 512, 512,
                sqn + (size_t)g * 4 * N_, N_,
                dist, (long long)N_ * N_, N_, C);
            select_kernel<<<2048, 256, 0, stream>>>(dist, idx + (size_t)g * 4 * N_ * KNN);
        }
        mfma_gemm<0><<<dim3(256, N2 / 128, 1), 256, 0, stream>>>(
            cathi + coloff, catlo + coloff, 0, 512,
            Bth, Btl, 0, C,
            bt, 0,
            ut, 0, N2, C);
        if (Cout == 64)       gather_max_kernel<64><<<8192, 256, 0, stream>>>(ut, idx, cathi, catlo, colout);
        else if (Cout == 128) gather_max_kernel<128><<<16384, 256, 0, stream>>>(ut, idx, cathi, catlo, colout);
        else                  gather_max_kernel<256><<<32768, 256, 0, stream>>>(ut, idx, cathi, catlo, colout);
    };
    conv(0, 64, 64, w2, b2, 64);
    conv(64, 64, 128, w3, b3, 128);
    conv(128, 128, 256, w4, b4, 256);

    // ---- w5 + leaky + max over N (fused epilogue) ----
    prep_w5_kernel<<<2048, 256, 0, stream>>>(w5, Bth, Btl);
    mfma_gemm<1><<<dim3(256, 8, 1), 256, 0, stream>>>(
        cathi, catlo, 0, 512,
        Bth, Btl, 0, 512,
        b5, 0,
        gpart, 0, 1024, 512);
    featmax_kernel<<<64, 256, 0, stream>>>(gpart, feat);

    fc_kernel<<<dim3(16, 16), 256, 0, stream>>>(feat, fw1, fb1, h1, 1024, 1);
    fc_kernel<<<dim3(16, 16), 256, 0, stream>>>(h1, fw2, fb2, h2, 1024, 1);
    fc_kernel<<<dim3(16, 48), 256, 0, stream>>>(h2, fw3, fb3, coarse, 3072, 0);

    chamferA_kernel<<<dim3(16, 32), 256, 0, stream>>>(coarse, pts, pA);
    chamferB_kernel<<<dim3(16, 32), 256, 0, stream>>>(coarse, pts, pB);
    loss_kernel<<<1, 256, 0, stream>>>(pA, pB, out);
}